// Round 6
// baseline (774.488 us; speedup 1.0000x reference)
//
#include <hip/hip_runtime.h>
#include <hip/hip_bf16.h>
#include <math.h>

#define H 2048
#define IMOE 1408
#define NEXP 8
#define T_TOK 2048
#define ISH 2816
#define SCALEF 2.5f

#define NT_GU_R (IMOE / 64)   // 22
#define NT_GU_S (ISH / 64)    // 44
#define NT_DN   (H / 128)     // 16
#define GU_GRID (39 * NT_GU_R + 16 * NT_GU_S)  // 1562
#define DN_GRID (39 * NT_DN + 16 * NT_DN)      // 880
#define LHALF 8192            // shorts per LDS buffer half (128*64)

typedef __attribute__((ext_vector_type(8))) short short8;
typedef __attribute__((ext_vector_type(4))) short short4v;
typedef __attribute__((ext_vector_type(4))) float floatx4;

union U8 { short8 s; unsigned u[4]; };

__device__ inline float b2f(short v) {
    unsigned int u = ((unsigned int)(unsigned short)v) << 16;
    float f; __builtin_memcpy(&f, &u, 4); return f;
}
__device__ inline short f2b(float f) {
    __hip_bfloat16 h = __float2bfloat16(f);
    short s; __builtin_memcpy(&s, &h, 2); return s;
}
__device__ __forceinline__ unsigned pkbf16(float a, float b) {
    float2 t; t.x = a; t.y = b;
    __hip_bfloat162 h2 = __float22bfloat162_rn(t);
    unsigned u; __builtin_memcpy(&u, &h2, 4); return u;
}

// async 16B/lane global->LDS; LDS dest = wave-uniform base + lane*16
__device__ __forceinline__ void async16(const short* g, short* l) {
    __builtin_amdgcn_global_load_lds(
        (const __attribute__((address_space(1))) unsigned*)g,
        (__attribute__((address_space(3))) unsigned*)l, 16, 0, 0);
}

// Bijective XCD-aware remap (m204): hardware assigns blockIdx%8 -> XCD.
__device__ __forceinline__ int xcd_map(int orig, int nwg) {
    int q = nwg >> 3, r = nwg & 7;
    int x = orig & 7, s = orig >> 3;
    int base = (x < r) ? x * (q + 1) : r * (q + 1) + (x - r) * q;
    return base + s;
}

// ---------------- Router (fp32 routing, matches reference; also emits bf16 x)
__global__ __launch_bounds__(256) void router_kernel(
    const float* __restrict__ x, const float* __restrict__ rw,
    const float* __restrict__ bias,
    int* __restrict__ cnt, int* __restrict__ tokList, int* __restrict__ slotList,
    float* __restrict__ pairW, short* __restrict__ xb)
{
    const int wid  = (blockIdx.x * 256 + threadIdx.x) >> 6;
    const int lane = threadIdx.x & 63;
    if (wid >= T_TOK) return;
    const float* xr = x + (size_t)wid * H;
    short* xbrow = xb + (size_t)wid * H;

    float acc[NEXP];
#pragma unroll
    for (int e = 0; e < NEXP; ++e) acc[e] = 0.f;

#pragma unroll
    for (int c = 0; c < 8; ++c) {
        int idx = (c * 64 + lane) * 4;
        floatx4 xv = *(const floatx4*)(xr + idx);
#pragma unroll
        for (int e = 0; e < NEXP; ++e) {
            floatx4 wv = *(const floatx4*)(rw + e * H + idx);
            acc[e] += xv.x * wv.x + xv.y * wv.y + xv.z * wv.z + xv.w * wv.w;
        }
        short4v o = { f2b(xv.x), f2b(xv.y), f2b(xv.z), f2b(xv.w) };
        *(short4v*)(xbrow + idx) = o;       // fused x fp32->bf16 convert
    }
#pragma unroll
    for (int e = 0; e < NEXP; ++e)
        for (int off = 32; off; off >>= 1)
            acc[e] += __shfl_xor(acc[e], off, 64);

    if (lane == 0) {
        float s[NEXP], sfc[NEXP];
#pragma unroll
        for (int e = 0; e < NEXP; ++e) {
            s[e]   = 1.0f / (1.0f + expf(-acc[e]));
            sfc[e] = s[e] + bias[e];
        }
        float gs[4];
#pragma unroll
        for (int g = 0; g < 4; ++g) gs[g] = sfc[2 * g] + sfc[2 * g + 1];
        int g1 = 0;
        for (int g = 1; g < 4; ++g) if (gs[g] > gs[g1]) g1 = g;
        int g2 = -1;
        for (int g = 0; g < 4; ++g) {
            if (g == g1) continue;
            if (g2 < 0 || gs[g] > gs[g2]) g2 = g;
        }
        float msk[NEXP];
#pragma unroll
        for (int e = 0; e < NEXP; ++e) {
            int g = e >> 1;
            msk[e] = (g == g1 || g == g2) ? sfc[e] : 0.0f;
        }
        int e1 = 0;
        for (int e = 1; e < NEXP; ++e) if (msk[e] > msk[e1]) e1 = e;
        int e2 = -1;
        for (int e = 0; e < NEXP; ++e) {
            if (e == e1) continue;
            if (e2 < 0 || msk[e] > msk[e2]) e2 = e;
        }
        float w1 = s[e1], w2 = s[e2];
        float inv = SCALEF / (w1 + w2 + 1e-20f);
        w1 *= inv; w2 *= inv;
        int p1 = atomicAdd(&cnt[e1], 1);
        tokList[e1 * T_TOK + p1]  = wid;
        slotList[e1 * T_TOK + p1] = 2 * wid;
        pairW[2 * wid] = w1;
        int p2 = atomicAdd(&cnt[e2], 1);
        tokList[e2 * T_TOK + p2]  = wid;
        slotList[e2 * T_TOK + p2] = 2 * wid + 1;
        pairW[2 * wid + 1] = w2;
    }
}

// ---------------- Plan ----------------
// meta[0..8]  : M per entry (entry 8 = shared, 2048)
// meta[9..17] : compact row base
// meta[20..29]: gate/up item starts
// meta[32..41]: down item starts (meta[40]=routed end)
__global__ void plan_kernel(const int* __restrict__ cnt, int* __restrict__ meta)
{
    if (blockIdx.x != 0 || threadIdx.x != 0) return;
    int base = 0, gu = 0, dn = 0;
    meta[20] = 0; meta[32] = 0;
    for (int e = 0; e < NEXP; ++e) {
        int M = cnt[e];
        meta[e] = M;
        meta[9 + e] = base;
        base += M;
        int MT = (M + 127) >> 7;
        gu += MT * NT_GU_R;
        dn += MT * NT_DN;
        meta[21 + e] = gu;
        meta[33 + e] = dn;
    }
    meta[8]  = T_TOK;   // shared M
    meta[17] = 0;       // shared base (separate buffer)
    meta[29] = gu + 16 * NT_GU_S;
    meta[41] = dn + 16 * NT_DN;
}

// ---------------- Fused gate+up grouped GEMM ----------------
// BM=128, BN=64 per matrix, BK=64, K=2048. A bf16 via async16 (dbuf);
// B fp32 weights reg-staged with T14 async split: issue 8 global_load_dwordx4
// EARLY (before compute), cvt_pk + swizzled ds_write LATE (after compute) ->
// HBM latency + cvt VALU hide under the 32-MFMA cluster, and the LDS->MFMA
// read path stays pure bf16 ds_read_b128 (round-3's fast path) with no
// standalone wconvert pass (round-5's win). One counted drain + raw
// s_barrier per K-step.
__global__ __launch_bounds__(256) void gu_gemm(
    const short* __restrict__ xb,
    const float* __restrict__ gw, const float* __restrict__ uw,
    const float* __restrict__ sgw, const float* __restrict__ suw,
    short* __restrict__ hiddenP, short* __restrict__ hiddenS,
    const int* __restrict__ tokList, const int* __restrict__ meta)
{
    const int total = meta[29];
    if (blockIdx.x >= total) return;
    const int idx = xcd_map(blockIdx.x, total);
    int e = 0;
    while (e < 8 && idx >= meta[21 + e]) ++e;

    int M, NT, Nout, rowBase;
    const float *b1, *b2;
    const int* gat;
    short* outP;
    if (e < 8) {
        M = meta[e]; NT = NT_GU_R; Nout = IMOE; rowBase = meta[9 + e];
        b1 = gw + (size_t)e * IMOE * H;
        b2 = uw + (size_t)e * IMOE * H;
        gat = tokList + e * T_TOK;
        outP = hiddenP;
    } else {
        M = T_TOK; NT = NT_GU_S; Nout = ISH; rowBase = 0;
        b1 = sgw; b2 = suw; gat = nullptr; outP = hiddenS;
    }
    const int MT = (M + 127) >> 7;
    const int local = idx - meta[20 + e];
    const int mt = local % MT;          // mt-minor: adjacent blocks share weight tile
    const int nt = local / MT;

    __shared__ short As[2 * LHALF];     // bf16 A, dbuf
    __shared__ short Bgu[2 * LHALF];    // bf16 B (rows 0..63 gate, 64..127 up), dbuf

    const int tid  = threadIdx.x;
    const int w    = tid >> 6;
    const int lane = tid & 63;
    const int quad = lane >> 4;
    const int l16  = lane & 15;
    const int wm = w >> 1, wn = w & 1;

    // A staging: async16, pre-swizzled source chunk, linear dest
    const int r8 = lane >> 3;
    const int csA = (lane & 7) ^ r8;
    const short* aSrc[4];
    short* ldsA[4];
#pragma unroll
    for (int i = 0; i < 4; ++i) {
        int r = w * 32 + i * 8 + r8;
        int p = mt * 128 + r;
        int pos = p < M ? p : (M - 1);
        int arow = gat ? gat[pos] : pos;
        aSrc[i] = xb + (size_t)arow * H + csA * 8;
        ldsA[i] = As + (w * 32 + i * 8) * 64;
    }

    // B reg-staging: thread -> combined row (0..127), col half (32 floats)
    const int brow  = tid >> 1;
    const int bhalf = tid & 1;
    const float* bsrc = ((brow < 64) ? (b1 + (size_t)(nt * 64 + brow) * H)
                                     : (b2 + (size_t)(nt * 64 + brow - 64) * H))
                        + bhalf * 32;
    // swizzled dest chunk offsets (phys = logical ^ (row&7); matches read path)
    int bDstOff[4];
#pragma unroll
    for (int j = 0; j < 4; ++j)
        bDstOff[j] = brow * 64 + (((bhalf * 4 + j) ^ (brow & 7)) * 8);

    floatx4 accg[4][2] = {};
    floatx4 accu[4][2] = {};

    // ---- prologue: stage tile 0 into buffer 0 ----
    {
        floatx4 breg[8];
#pragma unroll
        for (int j = 0; j < 4; ++j) {
            breg[2 * j]     = *(const floatx4*)(bsrc + j * 8);
            breg[2 * j + 1] = *(const floatx4*)(bsrc + j * 8 + 4);
        }
#pragma unroll
        for (int i = 0; i < 4; ++i) async16(aSrc[i], ldsA[i]);
#pragma unroll
        for (int j = 0; j < 4; ++j) {
            U8 t;
            t.u[0] = pkbf16(breg[2*j].x,   breg[2*j].y);
            t.u[1] = pkbf16(breg[2*j].z,   breg[2*j].w);
            t.u[2] = pkbf16(breg[2*j+1].x, breg[2*j+1].y);
            t.u[3] = pkbf16(breg[2*j+1].z, breg[2*j+1].w);
            *(short8*)(Bgu + bDstOff[j]) = t.s;
        }
        asm volatile("s_waitcnt vmcnt(0) lgkmcnt(0)" ::: "memory");
        __builtin_amdgcn_s_barrier();
    }

    int cur = 0;
    for (int k0 = 0; k0 < H; k0 += 64) {
        const int nk = k0 + 64;
        const int has_next = (nk < H);
        const int noff = (cur ^ 1) * LHALF;

        floatx4 breg[8];
        if (has_next) {
            // issue-early: B regs then A async16 (overlap under compute)
#pragma unroll
            for (int j = 0; j < 4; ++j) {
                breg[2 * j]     = *(const floatx4*)(bsrc + nk + j * 8);
                breg[2 * j + 1] = *(const floatx4*)(bsrc + nk + j * 8 + 4);
            }
#pragma unroll
            for (int i = 0; i < 4; ++i) async16(aSrc[i] + nk, ldsA[i] + noff);
        }

        // compute current buffer: pure bf16 ds_read_b128 + MFMA
        const short* Ab = As  + cur * LHALF;
        const short* Bb = Bgu + cur * LHALF;
        const int sw = l16 & 7;
        short8 af[4], bgf[2], buf[2];
#pragma unroll
        for (int kk2 = 0; kk2 < 2; ++kk2) {
            const int c = kk2 * 4 + quad;
#pragma unroll
            for (int m = 0; m < 4; ++m)
                af[m] = *(const short8*)(Ab + (wm * 64 + m * 16 + l16) * 64 + (c ^ sw) * 8);
#pragma unroll
            for (int n = 0; n < 2; ++n) {
                bgf[n] = *(const short8*)(Bb + (wn * 32 + n * 16 + l16) * 64 + (c ^ sw) * 8);
                buf[n] = *(const short8*)(Bb + (64 + wn * 32 + n * 16 + l16) * 64 + (c ^ sw) * 8);
            }
#pragma unroll
            for (int m = 0; m < 4; ++m)
#pragma unroll
                for (int n = 0; n < 2; ++n) {
                    accg[m][n] = __builtin_amdgcn_mfma_f32_16x16x32_bf16(af[m], bgf[n], accg[m][n], 0, 0, 0);
                    accu[m][n] = __builtin_amdgcn_mfma_f32_16x16x32_bf16(af[m], buf[n], accu[m][n], 0, 0, 0);
                }
        }

        if (has_next) {
            // write-late: cvt + swizzled ds_write into the other buffer
#pragma unroll
            for (int j = 0; j < 4; ++j) {
                U8 t;
                t.u[0] = pkbf16(breg[2*j].x,   breg[2*j].y);
                t.u[1] = pkbf16(breg[2*j].z,   breg[2*j].w);
                t.u[2] = pkbf16(breg[2*j+1].x, breg[2*j+1].y);
                t.u[3] = pkbf16(breg[2*j+1].z, breg[2*j+1].w);
                *(short8*)(Bgu + noff + bDstOff[j]) = t.s;
            }
        }
        asm volatile("s_waitcnt vmcnt(0) lgkmcnt(0)" ::: "memory");
        __builtin_amdgcn_s_barrier();
        cur ^= 1;
    }

    // epilogue: silu(g)*u -> compact hidden. C/D layout: col=l16, row=quad*4+rr
#pragma unroll
    for (int m = 0; m < 4; ++m) {
#pragma unroll
        for (int rr = 0; rr < 4; ++rr) {
            int lr = wm * 64 + m * 16 + quad * 4 + rr;
            int p = mt * 128 + lr;
            if (p >= M) continue;
            size_t rowoff = (size_t)(rowBase + p) * Nout + nt * 64 + wn * 32;
#pragma unroll
            for (int n = 0; n < 2; ++n) {
                float g = accg[m][n][rr];
                float u = accu[m][n][rr];
                outP[rowoff + n * 16 + l16] = f2b(g / (1.0f + __expf(-g)) * u);
            }
        }
    }
}

// ---------------- Down grouped GEMM ----------------
// BM=128, BN=128, BK=64, K = 1408 (routed) / 2816 (shared). Same T14
// reg-staged B pipeline. Per-range XCD remap keeps L2 locality AND per-XCD
// work balance (round-1 lesson).
__global__ __launch_bounds__(256) void dn_gemm(
    const short* __restrict__ hiddenP, const short* __restrict__ hiddenS,
    const float* __restrict__ dw, const float* __restrict__ sdw,
    short* __restrict__ outPairs, short* __restrict__ sharedOut,
    const int* __restrict__ slotList, const int* __restrict__ meta)
{
    const int total = meta[41];
    if (blockIdx.x >= total) return;
    const int rtot = meta[40];
    int idx;
    if (blockIdx.x < rtot) idx = xcd_map(blockIdx.x, rtot);
    else                   idx = rtot + xcd_map(blockIdx.x - rtot, total - rtot);
    int e = 0;
    while (e < 8 && idx >= meta[33 + e]) ++e;

    int M, K, rowBase;
    const float* bp;
    const short* Abase;
    const int* scat;
    short* outP;
    if (e < 8) {
        M = meta[e]; K = IMOE; rowBase = meta[9 + e];
        bp = dw + (size_t)e * H * IMOE;
        Abase = hiddenP; scat = slotList + e * T_TOK; outP = outPairs;
    } else {
        M = T_TOK; K = ISH; rowBase = 0;
        bp = sdw; Abase = hiddenS; scat = nullptr; outP = sharedOut;
    }
    const int MT = (M + 127) >> 7;
    const int local = idx - meta[32 + e];
    const int mt = local % MT;
    const int nt = local / MT;

    __shared__ short As[2 * LHALF];
    __shared__ short Bs[2 * LHALF];

    const int tid  = threadIdx.x;
    const int w    = tid >> 6;
    const int lane = tid & 63;
    const int quad = lane >> 4;
    const int l16  = lane & 15;
    const int wm = w >> 1, wn = w & 1;

    const int r8 = lane >> 3;
    const int csA = (lane & 7) ^ r8;
    const short* aSrc[4];
    short* ldsA[4];
#pragma unroll
    for (int i = 0; i < 4; ++i) {
        int r = w * 32 + i * 8 + r8;
        int p = mt * 128 + r;
        int pos = p < M ? p : (M - 1);
        aSrc[i] = Abase + (size_t)(rowBase + pos) * K + csA * 8;
        ldsA[i] = As + (w * 32 + i * 8) * 64;
    }

    const int brow  = tid >> 1;
    const int bhalf = tid & 1;
    const float* bsrc = bp + (size_t)(nt * 128 + brow) * K + bhalf * 32;
    int bDstOff[4];
#pragma unroll
    for (int j = 0; j < 4; ++j)
        bDstOff[j] = brow * 64 + (((bhalf * 4 + j) ^ (brow & 7)) * 8);

    floatx4 acc[4][4] = {};

    // ---- prologue ----
    {
        floatx4 breg[8];
#pragma unroll
        for (int j = 0; j < 4; ++j) {
            breg[2 * j]     = *(const floatx4*)(bsrc + j * 8);
            breg[2 * j + 1] = *(const floatx4*)(bsrc + j * 8 + 4);
        }
#pragma unroll
        for (int i = 0; i < 4; ++i) async16(aSrc[i], ldsA[i]);
#pragma unroll
        for (int j = 0; j < 4; ++j) {
            U8 t;
            t.u[0] = pkbf16(breg[2*j].x,   breg[2*j].y);
            t.u[1] = pkbf16(breg[2*j].z,   breg[2*j].w);
            t.u[2] = pkbf16(breg[2*j+1].x, breg[2*j+1].y);
            t.u[3] = pkbf16(breg[2*j+1].z, breg[2*j+1].w);
            *(short8*)(Bs + bDstOff[j]) = t.s;
        }
        asm volatile("s_waitcnt vmcnt(0) lgkmcnt(0)" ::: "memory");
        __builtin_amdgcn_s_barrier();
    }

    const int kIters = K >> 6;
    int cur = 0;
    for (int kt = 0; kt < kIters; ++kt) {
        const int nk = (kt + 1) << 6;
        const int has_next = (kt + 1 < kIters);
        const int noff = (cur ^ 1) * LHALF;

        floatx4 breg[8];
        if (has_next) {
#pragma unroll
            for (int j = 0; j < 4; ++j) {
                breg[2 * j]     = *(const floatx4*)(bsrc + nk + j * 8);
                breg[2 * j + 1] = *(const floatx4*)(bsrc + nk + j * 8 + 4);
            }
#pragma unroll
            for (int i = 0; i < 4; ++i) async16(aSrc[i] + nk, ldsA[i] + noff);
        }

        const short* Ab = As + cur * LHALF;
        const short* Bb = Bs + cur * LHALF;
        const int sw = l16 & 7;
        short8 af[4], bf[4];
#pragma unroll
        for (int kk2 = 0; kk2 < 2; ++kk2) {
            const int c = kk2 * 4 + quad;
#pragma unroll
            for (int m = 0; m < 4; ++m)
                af[m] = *(const short8*)(Ab + (wm * 64 + m * 16 + l16) * 64 + (c ^ sw) * 8);
#pragma unroll
            for (int n = 0; n < 4; ++n)
                bf[n] = *(const short8*)(Bb + (wn * 64 + n * 16 + l16) * 64 + (c ^ sw) * 8);
#pragma unroll
            for (int m = 0; m < 4; ++m)
#pragma unroll
                for (int n = 0; n < 4; ++n)
                    acc[m][n] = __builtin_amdgcn_mfma_f32_16x16x32_bf16(af[m], bf[n], acc[m][n], 0, 0, 0);
        }

        if (has_next) {
#pragma unroll
            for (int j = 0; j < 4; ++j) {
                U8 t;
                t.u[0] = pkbf16(breg[2*j].x,   breg[2*j].y);
                t.u[1] = pkbf16(breg[2*j].z,   breg[2*j].w);
                t.u[2] = pkbf16(breg[2*j+1].x, breg[2*j+1].y);
                t.u[3] = pkbf16(breg[2*j+1].z, breg[2*j+1].w);
                *(short8*)(Bs + noff + bDstOff[j]) = t.s;
            }
        }
        asm volatile("s_waitcnt vmcnt(0) lgkmcnt(0)" ::: "memory");
        __builtin_amdgcn_s_barrier();
        cur ^= 1;
    }

#pragma unroll
    for (int m = 0; m < 4; ++m) {
#pragma unroll
        for (int rr = 0; rr < 4; ++rr) {
            int lr = wm * 64 + m * 16 + quad * 4 + rr;
            int p = mt * 128 + lr;
            if (p >= M) continue;
            int crow = scat ? scat[p] : p;
            size_t rowoff = (size_t)crow * H + nt * 128 + wn * 64;
#pragma unroll
            for (int n = 0; n < 4; ++n)
                outP[rowoff + n * 16 + l16] = f2b(acc[m][n][rr]);
        }
    }
}

// ---------------- Combine ----------------
__global__ __launch_bounds__(256) void combine_kernel(
    const short* __restrict__ outPairs, const short* __restrict__ sharedOut,
    const float* __restrict__ pairW, float* __restrict__ out)
{
    size_t gi = ((size_t)blockIdx.x * 256 + threadIdx.x) * 8;
    int t = (int)(gi >> 11);
    int h = (int)(gi & (H - 1));
    float w0 = pairW[2 * t], w1 = pairW[2 * t + 1];
    short8 p0 = *(const short8*)(outPairs + (size_t)(2 * t) * H + h);
    short8 p1 = *(const short8*)(outPairs + (size_t)(2 * t + 1) * H + h);
    short8 sh = *(const short8*)(sharedOut + gi);
    floatx4 o0, o1;
#pragma unroll
    for (int j = 0; j < 4; ++j)
        o0[j] = w0 * b2f(p0[j]) + w1 * b2f(p1[j]) + b2f(sh[j]);
#pragma unroll
    for (int j = 0; j < 4; ++j)
        o1[j] = w0 * b2f(p0[4 + j]) + w1 * b2f(p1[4 + j]) + b2f(sh[4 + j]);
    *(floatx4*)(out + gi)     = o0;
    *(floatx4*)(out + gi + 4) = o1;
}

extern "C" void kernel_launch(void* const* d_in, const int* in_sizes, int n_in,
                              void* d_out, int out_size, void* d_ws, size_t ws_size,
                              hipStream_t stream)
{
    const float* x    = (const float*)d_in[0];
    const float* rw   = (const float*)d_in[1];
    const float* bias = (const float*)d_in[2];
    const float* gw   = (const float*)d_in[3];
    const float* uw   = (const float*)d_in[4];
    const float* dw   = (const float*)d_in[5];
    const float* sgw  = (const float*)d_in[6];
    const float* suw  = (const float*)d_in[7];
    const float* sdw  = (const float*)d_in[8];
    float* out = (float*)d_out;

    char* ws = (char*)d_ws;
    size_t off = 0;
    auto alloc = [&](size_t bytes) {
        off = (off + 255) & ~(size_t)255;
        void* p = ws + off;
        off += bytes;
        return p;
    };
    int*   cnt       = (int*)  alloc(NEXP * sizeof(int));
    int*   tokList   = (int*)  alloc((size_t)NEXP * T_TOK * sizeof(int));
    int*   slotList  = (int*)  alloc((size_t)NEXP * T_TOK * sizeof(int));
    float* pairW     = (float*)alloc((size_t)2 * T_TOK * sizeof(float));
    int*   meta      = (int*)  alloc(64 * sizeof(int));
    short* xb        = (short*)alloc((size_t)T_TOK * H * sizeof(short));
    short* hiddenP   = (short*)alloc((size_t)2 * T_TOK * IMOE * sizeof(short));
    short* hiddenS   = (short*)alloc((size_t)T_TOK * ISH * sizeof(short));
    short* outPairs  = (short*)alloc((size_t)2 * T_TOK * H * sizeof(short));
    short* sharedOut = (short*)alloc((size_t)T_TOK * H * sizeof(short));
    (void)ws_size;

    hipMemsetAsync(cnt, 0, NEXP * sizeof(int), stream);

    router_kernel<<<T_TOK / 4, 256, 0, stream>>>(x, rw, bias, cnt, tokList, slotList, pairW, xb);
    plan_kernel<<<1, 64, 0, stream>>>(cnt, meta);

    gu_gemm<<<GU_GRID, 256, 0, stream>>>(xb, gw, uw, sgw, suw,
                                         hiddenP, hiddenS, tokList, meta);
    dn_gemm<<<DN_GRID, 256, 0, stream>>>(hiddenP, hiddenS, dw, sdw,
                                         outPairs, sharedOut, slotList, meta);

    combine_kernel<<<(T_TOK * H / 8) / 256, 256, 0, stream>>>(outPairs, sharedOut, pairW, out);
}

// Round 7
// 579.377 us; speedup vs baseline: 1.3368x; 1.3368x over previous
//
#include <hip/hip_runtime.h>
#include <hip/hip_bf16.h>
#include <math.h>

#define H 2048
#define IMOE 1408
#define NEXP 8
#define T_TOK 2048
#define ISH 2816
#define SCALEF 2.5f

#define NT_GU_R (IMOE / 64)   // 22
#define NT_GU_S (ISH / 64)    // 44
#define NT_DN   (H / 128)     // 16
#define GU_GRID (39 * NT_GU_R + 16 * NT_GU_S)  // 1562 (max)
#define DN_GRID (39 * NT_DN + 16 * NT_DN)      // 880

// weight-conversion unit = 8 floats
#define W8_GU  2883584   // 8*1408*2048/8 (gw, uw, dw each)
#define W8_SH  720896    // 2816*2048/8   (sgw, suw, sdw each)
#define GUW8   (2 * W8_GU + 2 * W8_SH)   // gw+uw+sgw+suw units
#define DNW8   (W8_GU + W8_SH)           // dw+sdw units

typedef __attribute__((ext_vector_type(8))) short short8;
typedef __attribute__((ext_vector_type(4))) short short4v;
typedef __attribute__((ext_vector_type(4))) float floatx4;

__device__ inline float b2f(short v) {
    unsigned int u = ((unsigned int)(unsigned short)v) << 16;
    float f; __builtin_memcpy(&f, &u, 4); return f;
}
__device__ inline short f2b(float f) {
    __hip_bfloat16 h = __float2bfloat16(f);
    short s; __builtin_memcpy(&s, &h, 2); return s;
}

// async 16B/lane global->LDS; LDS dest = wave-uniform base + lane*16
__device__ __forceinline__ void async16(const short* g, short* l) {
    __builtin_amdgcn_global_load_lds(
        (const __attribute__((address_space(1))) unsigned*)g,
        (__attribute__((address_space(3))) unsigned*)l, 16, 0, 0);
}

// Bijective XCD-aware remap (m204): hardware assigns blockIdx%8 -> XCD.
__device__ __forceinline__ int xcd_map(int orig, int nwg) {
    int q = nwg >> 3, r = nwg & 7;
    int x = orig & 7, s = orig >> 3;
    int base = (x < r) ? x * (q + 1) : r * (q + 1) + (x - r) * q;
    return base + s;
}

__device__ __forceinline__ void cvt8(const float* s, short* d, size_t local) {
    floatx4 v0 = *(const floatx4*)(s + local * 8);
    floatx4 v1 = *(const floatx4*)(s + local * 8 + 4);
    short8 o = { f2b(v0.x), f2b(v0.y), f2b(v0.z), f2b(v0.w),
                 f2b(v1.x), f2b(v1.y), f2b(v1.z), f2b(v1.w) };
    *(short8*)(d + local * 8) = o;
}

// ---------------- Fused router + gate/up weight convert ----------------
// Blocks 0..511: routing (fp32, matches reference exactly; no atomics —
// writes per-token picks; list building moved to build_lists). Also emits
// bf16 x. Blocks 512..2559: stream-convert gw/uw/sgw/suw to bf16 (345 MB,
// ~55us BW-bound) — the router's ~10us critical path hides under it, and
// the old serial convert+wconvert launches (~100us) disappear.
__global__ __launch_bounds__(256) void route_conv_kernel(
    const float* __restrict__ x, const float* __restrict__ rw,
    const float* __restrict__ bias,
    float* __restrict__ pairW, int2* __restrict__ pickE, short* __restrict__ xb,
    const float* __restrict__ gw, const float* __restrict__ uw,
    const float* __restrict__ sgw, const float* __restrict__ suw,
    short* __restrict__ gwb, short* __restrict__ uwb,
    short* __restrict__ sgwb, short* __restrict__ suwb)
{
    if (blockIdx.x >= 512) {
        int u = (blockIdx.x - 512) * 256 + threadIdx.x;
        for (; u < GUW8; u += 2048 * 256) {
            const float* s; short* d; int local;
            if (u < W8_GU)               { s = gw;  d = gwb;  local = u; }
            else if (u < 2 * W8_GU)      { s = uw;  d = uwb;  local = u - W8_GU; }
            else if (u < 2 * W8_GU + W8_SH) { s = sgw; d = sgwb; local = u - 2 * W8_GU; }
            else                         { s = suw; d = suwb; local = u - 2 * W8_GU - W8_SH; }
            cvt8(s, d, (size_t)local);
        }
        return;
    }

    const int wid  = (blockIdx.x * 256 + threadIdx.x) >> 6;
    const int lane = threadIdx.x & 63;
    const float* xr = x + (size_t)wid * H;
    short* xbrow = xb + (size_t)wid * H;

    float acc[NEXP];
#pragma unroll
    for (int e = 0; e < NEXP; ++e) acc[e] = 0.f;

#pragma unroll
    for (int c = 0; c < 8; ++c) {
        int idx = (c * 64 + lane) * 4;
        floatx4 xv = *(const floatx4*)(xr + idx);
#pragma unroll
        for (int e = 0; e < NEXP; ++e) {
            floatx4 wv = *(const floatx4*)(rw + e * H + idx);
            acc[e] += xv.x * wv.x + xv.y * wv.y + xv.z * wv.z + xv.w * wv.w;
        }
        short4v o = { f2b(xv.x), f2b(xv.y), f2b(xv.z), f2b(xv.w) };
        *(short4v*)(xbrow + idx) = o;       // fused x fp32->bf16 convert
    }
#pragma unroll
    for (int e = 0; e < NEXP; ++e)
        for (int off = 32; off; off >>= 1)
            acc[e] += __shfl_xor(acc[e], off, 64);

    if (lane == 0) {
        float s[NEXP], sfc[NEXP];
#pragma unroll
        for (int e = 0; e < NEXP; ++e) {
            s[e]   = 1.0f / (1.0f + expf(-acc[e]));
            sfc[e] = s[e] + bias[e];
        }
        float gs[4];
#pragma unroll
        for (int g = 0; g < 4; ++g) gs[g] = sfc[2 * g] + sfc[2 * g + 1];
        int g1 = 0;
        for (int g = 1; g < 4; ++g) if (gs[g] > gs[g1]) g1 = g;
        int g2 = -1;
        for (int g = 0; g < 4; ++g) {
            if (g == g1) continue;
            if (g2 < 0 || gs[g] > gs[g2]) g2 = g;
        }
        float msk[NEXP];
#pragma unroll
        for (int e = 0; e < NEXP; ++e) {
            int g = e >> 1;
            msk[e] = (g == g1 || g == g2) ? sfc[e] : 0.0f;
        }
        int e1 = 0;
        for (int e = 1; e < NEXP; ++e) if (msk[e] > msk[e1]) e1 = e;
        int e2 = -1;
        for (int e = 0; e < NEXP; ++e) {
            if (e == e1) continue;
            if (e2 < 0 || msk[e] > msk[e2]) e2 = e;
        }
        float w1 = s[e1], w2 = s[e2];
        float inv = SCALEF / (w1 + w2 + 1e-20f);
        pairW[2 * wid]     = w1 * inv;
        pairW[2 * wid + 1] = w2 * inv;
        int2 pk; pk.x = e1; pk.y = e2;
        pickE[wid] = pk;
    }
}

// ---------------- Build per-expert token lists (no atomics) ----------------
// 8 blocks (one per expert) x 256 threads; LDS prefix-scan compaction over
// 2048 tokens. Deterministic token-ascending order (also improves A-gather
// locality). Replaces the router's serialized global atomicAdds (G12).
__global__ __launch_bounds__(256) void build_lists(
    const int2* __restrict__ pickE, int* __restrict__ cnt,
    int* __restrict__ tokList, int* __restrict__ slotList)
{
    const int e = blockIdx.x;
    const int tid = threadIdx.x;
    __shared__ int pre[256];
    const int t0 = tid * 8;
    int2 p[8];
#pragma unroll
    for (int j = 0; j < 8; ++j) p[j] = pickE[t0 + j];
    int cme = 0;
#pragma unroll
    for (int j = 0; j < 8; ++j) cme += (p[j].x == e || p[j].y == e) ? 1 : 0;
    pre[tid] = cme;
    __syncthreads();
    for (int off = 1; off < 256; off <<= 1) {
        int v = (tid >= off) ? pre[tid - off] : 0;
        __syncthreads();
        pre[tid] += v;
        __syncthreads();
    }
    int base = pre[tid] - cme;   // exclusive prefix
#pragma unroll
    for (int j = 0; j < 8; ++j) {
        if (p[j].x == e || p[j].y == e) {
            tokList[e * T_TOK + base]  = t0 + j;
            slotList[e * T_TOK + base] = 2 * (t0 + j) + (p[j].x == e ? 0 : 1);
            ++base;
        }
    }
    if (tid == 255) cnt[e] = pre[255];
}

// ---------------- Plan ----------------
// meta[0..8]  : M per entry (entry 8 = shared, 2048)
// meta[9..17] : compact row base
// meta[20..29]: gate/up item starts
// meta[32..41]: down item starts (meta[40]=routed end)
__global__ void plan_kernel(const int* __restrict__ cnt, int* __restrict__ meta)
{
    if (blockIdx.x != 0 || threadIdx.x != 0) return;
    int base = 0, gu = 0, dn = 0;
    meta[20] = 0; meta[32] = 0;
    for (int e = 0; e < NEXP; ++e) {
        int M = cnt[e];
        meta[e] = M;
        meta[9 + e] = base;
        base += M;
        int MT = (M + 127) >> 7;
        gu += MT * NT_GU_R;
        dn += MT * NT_DN;
        meta[21 + e] = gu;
        meta[33 + e] = dn;
    }
    meta[8]  = T_TOK;   // shared M
    meta[17] = 0;       // shared base (separate buffer)
    meta[29] = gu + 16 * NT_GU_S;
    meta[41] = dn + 16 * NT_DN;
}

// ---------------- Fused gate+up grouped GEMM (r3 structure, measured 152us)
// BM=128, BN=64 per matrix, BK=64, K=2048. A and B both bf16, both staged
// via async16 (pre-swizzled source / linear LDS dest / XOR-swizzled read),
// single-buffer 2-barrier (dbuf and T14 both measured null/negative).
// EXTRA: 512 rider blocks (ids >= meta[29]) stream-convert dw/sdw to bf16
// using gu's idle HBM bandwidth (gu runs at ~13% of peak) -> dn's weight
// conversion is hidden inside gu's window.
__global__ __launch_bounds__(256) void gu_gemm(
    const short* __restrict__ xb,
    const short* __restrict__ gwb, const short* __restrict__ uwb,
    const short* __restrict__ sgwb, const short* __restrict__ suwb,
    short* __restrict__ hiddenP, short* __restrict__ hiddenS,
    const int* __restrict__ tokList, const int* __restrict__ meta,
    const float* __restrict__ dw, const float* __restrict__ sdw,
    short* __restrict__ dwb, short* __restrict__ sdwb)
{
    const int total = meta[29];
    if (blockIdx.x >= total) {
        // rider role: convert dw/sdw (173 MB traffic) under gu's window
        int rid = blockIdx.x - total;
        if (rid >= 512) return;
        int u = rid * 256 + threadIdx.x;
        for (; u < DNW8; u += 512 * 256) {
            if (u < W8_GU) cvt8(dw, dwb, (size_t)u);
            else           cvt8(sdw, sdwb, (size_t)(u - W8_GU));
        }
        return;
    }
    const int idx = xcd_map(blockIdx.x, total);
    int e = 0;
    while (e < 8 && idx >= meta[21 + e]) ++e;

    int M, NT, Nout, rowBase;
    const short *b1, *b2;
    const int* gat;
    short* outP;
    if (e < 8) {
        M = meta[e]; NT = NT_GU_R; Nout = IMOE; rowBase = meta[9 + e];
        b1 = gwb + (size_t)e * IMOE * H;
        b2 = uwb + (size_t)e * IMOE * H;
        gat = tokList + e * T_TOK;
        outP = hiddenP;
    } else {
        M = T_TOK; NT = NT_GU_S; Nout = ISH; rowBase = 0;
        b1 = sgwb; b2 = suwb; gat = nullptr; outP = hiddenS;
    }
    const int MT = (M + 127) >> 7;
    const int local = idx - meta[20 + e];
    const int mt = local % MT;          // mt-minor: adjacent blocks share weight tile
    const int nt = local / MT;

    __shared__ short As[128 * 64];
    __shared__ short Bgu[128 * 64];     // rows 0..63 = gate, 64..127 = up

    const int tid  = threadIdx.x;
    const int w    = tid >> 6;
    const int lane = tid & 63;
    const int quad = lane >> 4;
    const int l16  = lane & 15;
    const int wm = w >> 1, wn = w & 1;

    const int r8 = lane >> 3;
    const int cs = (lane & 7) ^ r8;
    const short* aSrc[4];
    const short* bSrc[4];
    short* ldsA[4];
    short* ldsB[4];
#pragma unroll
    for (int i = 0; i < 4; ++i) {
        int r = w * 32 + i * 8 + r8;
        int p = mt * 128 + r;
        int pos = p < M ? p : (M - 1);
        int arow = gat ? gat[pos] : pos;
        aSrc[i] = xb + (size_t)arow * H + cs * 8;
        ldsA[i] = As + (w * 32 + i * 8) * 64;
        const short* wsrc = (r < 64) ? (b1 + (size_t)(nt * 64 + r) * H)
                                     : (b2 + (size_t)(nt * 64 + r - 64) * H);
        bSrc[i] = wsrc + cs * 8;
        ldsB[i] = Bgu + (w * 32 + i * 8) * 64;
    }

    floatx4 accg[4][2] = {};
    floatx4 accu[4][2] = {};

    for (int k0 = 0; k0 < H; k0 += 64) {
#pragma unroll
        for (int i = 0; i < 4; ++i) async16(aSrc[i] + k0, ldsA[i]);
#pragma unroll
        for (int i = 0; i < 4; ++i) async16(bSrc[i] + k0, ldsB[i]);
        __syncthreads();
        const int sw = l16 & 7;
        short8 af[4], bgf[2], buf[2];
#pragma unroll
        for (int kk2 = 0; kk2 < 2; ++kk2) {
            const int c = kk2 * 4 + quad;
#pragma unroll
            for (int m = 0; m < 4; ++m)
                af[m] = *(const short8*)(As + (wm * 64 + m * 16 + l16) * 64 + (c ^ sw) * 8);
#pragma unroll
            for (int n = 0; n < 2; ++n) {
                bgf[n] = *(const short8*)(Bgu + (wn * 32 + n * 16 + l16) * 64 + (c ^ sw) * 8);
                buf[n] = *(const short8*)(Bgu + (64 + wn * 32 + n * 16 + l16) * 64 + (c ^ sw) * 8);
            }
#pragma unroll
            for (int m = 0; m < 4; ++m)
#pragma unroll
                for (int n = 0; n < 2; ++n) {
                    accg[m][n] = __builtin_amdgcn_mfma_f32_16x16x32_bf16(af[m], bgf[n], accg[m][n], 0, 0, 0);
                    accu[m][n] = __builtin_amdgcn_mfma_f32_16x16x32_bf16(af[m], buf[n], accu[m][n], 0, 0, 0);
                }
        }
        __syncthreads();
    }

    // epilogue: silu(g)*u -> compact hidden. C/D layout: col=l16, row=quad*4+rr
#pragma unroll
    for (int m = 0; m < 4; ++m) {
#pragma unroll
        for (int rr = 0; rr < 4; ++rr) {
            int lr = wm * 64 + m * 16 + quad * 4 + rr;
            int p = mt * 128 + lr;
            if (p >= M) continue;
            size_t rowoff = (size_t)(rowBase + p) * Nout + nt * 64 + wn * 32;
#pragma unroll
            for (int n = 0; n < 2; ++n) {
                float g = accg[m][n][rr];
                float u = accu[m][n][rr];
                outP[rowoff + n * 16 + l16] = f2b(g / (1.0f + __expf(-g)) * u);
            }
        }
    }
}

// ---------------- Down grouped GEMM (r3 structure) ----------------
// BM=128, BN=128, BK=64, K = 1408 (routed) / 2816 (shared). bf16 B via
// async16 (converted by gu's riders). Per-range XCD remap keeps L2 locality
// AND per-XCD work balance (round-1 lesson).
__global__ __launch_bounds__(256) void dn_gemm(
    const short* __restrict__ hiddenP, const short* __restrict__ hiddenS,
    const short* __restrict__ dwb, const short* __restrict__ sdwb,
    short* __restrict__ outPairs, short* __restrict__ sharedOut,
    const int* __restrict__ slotList, const int* __restrict__ meta)
{
    const int total = meta[41];
    if (blockIdx.x >= total) return;
    const int rtot = meta[40];
    int idx;
    if (blockIdx.x < rtot) idx = xcd_map(blockIdx.x, rtot);
    else                   idx = rtot + xcd_map(blockIdx.x - rtot, total - rtot);
    int e = 0;
    while (e < 8 && idx >= meta[33 + e]) ++e;

    int M, K, rowBase;
    const short* bp;
    const short* Abase;
    const int* scat;
    short* outP;
    if (e < 8) {
        M = meta[e]; K = IMOE; rowBase = meta[9 + e];
        bp = dwb + (size_t)e * H * IMOE;
        Abase = hiddenP; scat = slotList + e * T_TOK; outP = outPairs;
    } else {
        M = T_TOK; K = ISH; rowBase = 0;
        bp = sdwb; Abase = hiddenS; scat = nullptr; outP = sharedOut;
    }
    const int MT = (M + 127) >> 7;
    const int local = idx - meta[32 + e];
    const int mt = local % MT;
    const int nt = local / MT;

    __shared__ short As[128 * 64];
    __shared__ short Bs[128 * 64];

    const int tid  = threadIdx.x;
    const int w    = tid >> 6;
    const int lane = tid & 63;
    const int quad = lane >> 4;
    const int l16  = lane & 15;
    const int wm = w >> 1, wn = w & 1;

    const int r8 = lane >> 3;
    const int cs = (lane & 7) ^ r8;
    const short* aSrc[4];
    const short* bSrc[4];
    short* ldsA[4];
    short* ldsB[4];
#pragma unroll
    for (int i = 0; i < 4; ++i) {
        int r = w * 32 + i * 8 + r8;
        int p = mt * 128 + r;
        int pos = p < M ? p : (M - 1);
        aSrc[i] = Abase + (size_t)(rowBase + pos) * K + cs * 8;
        ldsA[i] = As + (w * 32 + i * 8) * 64;
        bSrc[i] = bp + (size_t)(nt * 128 + r) * K + cs * 8;
        ldsB[i] = Bs + (w * 32 + i * 8) * 64;
    }

    floatx4 acc[4][4] = {};

    const int kIters = K >> 6;
    for (int kt = 0; kt < kIters; ++kt) {
        const int k0 = kt << 6;
#pragma unroll
        for (int i = 0; i < 4; ++i) async16(aSrc[i] + k0, ldsA[i]);
#pragma unroll
        for (int i = 0; i < 4; ++i) async16(bSrc[i] + k0, ldsB[i]);
        __syncthreads();
        const int sw = l16 & 7;
        short8 af[4], bf[4];
#pragma unroll
        for (int kk2 = 0; kk2 < 2; ++kk2) {
            const int c = kk2 * 4 + quad;
#pragma unroll
            for (int m = 0; m < 4; ++m)
                af[m] = *(const short8*)(As + (wm * 64 + m * 16 + l16) * 64 + (c ^ sw) * 8);
#pragma unroll
            for (int n = 0; n < 4; ++n)
                bf[n] = *(const short8*)(Bs + (wn * 64 + n * 16 + l16) * 64 + (c ^ sw) * 8);
#pragma unroll
            for (int m = 0; m < 4; ++m)
#pragma unroll
                for (int n = 0; n < 4; ++n)
                    acc[m][n] = __builtin_amdgcn_mfma_f32_16x16x32_bf16(af[m], bf[n], acc[m][n], 0, 0, 0);
        }
        __syncthreads();
    }

#pragma unroll
    for (int m = 0; m < 4; ++m) {
#pragma unroll
        for (int rr = 0; rr < 4; ++rr) {
            int lr = wm * 64 + m * 16 + quad * 4 + rr;
            int p = mt * 128 + lr;
            if (p >= M) continue;
            int crow = scat ? scat[p] : p;
            size_t rowoff = (size_t)crow * H + nt * 128 + wn * 64;
#pragma unroll
            for (int n = 0; n < 4; ++n)
                outP[rowoff + n * 16 + l16] = f2b(acc[m][n][rr]);
        }
    }
}

// ---------------- Combine ----------------
__global__ __launch_bounds__(256) void combine_kernel(
    const short* __restrict__ outPairs, const short* __restrict__ sharedOut,
    const float* __restrict__ pairW, float* __restrict__ out)
{
    size_t gi = ((size_t)blockIdx.x * 256 + threadIdx.x) * 8;
    int t = (int)(gi >> 11);
    int h = (int)(gi & (H - 1));
    float w0 = pairW[2 * t], w1 = pairW[2 * t + 1];
    short8 p0 = *(const short8*)(outPairs + (size_t)(2 * t) * H + h);
    short8 p1 = *(const short8*)(outPairs + (size_t)(2 * t + 1) * H + h);
    short8 sh = *(const short8*)(sharedOut + gi);
    floatx4 o0, o1;
#pragma unroll
    for (int j = 0; j < 4; ++j)
        o0[j] = w0 * b2f(p0[j]) + w1 * b2f(p1[j]) + b2f(sh[j]);
#pragma unroll
    for (int j = 0; j < 4; ++j)
        o1[j] = w0 * b2f(p0[4 + j]) + w1 * b2f(p1[4 + j]) + b2f(sh[4 + j]);
    *(floatx4*)(out + gi)     = o0;
    *(floatx4*)(out + gi + 4) = o1;
}

extern "C" void kernel_launch(void* const* d_in, const int* in_sizes, int n_in,
                              void* d_out, int out_size, void* d_ws, size_t ws_size,
                              hipStream_t stream)
{
    const float* x    = (const float*)d_in[0];
    const float* rw   = (const float*)d_in[1];
    const float* bias = (const float*)d_in[2];
    const float* gw   = (const float*)d_in[3];
    const float* uw   = (const float*)d_in[4];
    const float* dw   = (const float*)d_in[5];
    const float* sgw  = (const float*)d_in[6];
    const float* suw  = (const float*)d_in[7];
    const float* sdw  = (const float*)d_in[8];
    float* out = (float*)d_out;

    char* ws = (char*)d_ws;
    size_t off = 0;
    auto alloc = [&](size_t bytes) {
        off = (off + 255) & ~(size_t)255;
        void* p = ws + off;
        off += bytes;
        return p;
    };
    int*   cnt       = (int*)  alloc(NEXP * sizeof(int));
    int*   tokList   = (int*)  alloc((size_t)NEXP * T_TOK * sizeof(int));
    int*   slotList  = (int*)  alloc((size_t)NEXP * T_TOK * sizeof(int));
    float* pairW     = (float*)alloc((size_t)2 * T_TOK * sizeof(float));
    int2*  pickE     = (int2*) alloc((size_t)T_TOK * sizeof(int2));
    int*   meta      = (int*)  alloc(64 * sizeof(int));
    short* xb        = (short*)alloc((size_t)T_TOK * H * sizeof(short));
    short* hiddenP   = (short*)alloc((size_t)2 * T_TOK * IMOE * sizeof(short));
    short* hiddenS   = (short*)alloc((size_t)T_TOK * ISH * sizeof(short));
    short* outPairs  = (short*)alloc((size_t)2 * T_TOK * H * sizeof(short));
    short* sharedOut = (short*)alloc((size_t)T_TOK * H * sizeof(short));
    // bf16 weight copies (~173 MB total)
    short* gwb  = (short*)alloc((size_t)NEXP * IMOE * H * sizeof(short));
    short* uwb  = (short*)alloc((size_t)NEXP * IMOE * H * sizeof(short));
    short* dwb  = (short*)alloc((size_t)NEXP * H * IMOE * sizeof(short));
    short* sgwb = (short*)alloc((size_t)ISH * H * sizeof(short));
    short* suwb = (short*)alloc((size_t)ISH * H * sizeof(short));
    short* sdwb = (short*)alloc((size_t)H * ISH * sizeof(short));
    (void)ws_size;

    route_conv_kernel<<<2560, 256, 0, stream>>>(x, rw, bias, pairW, pickE, xb,
                                                gw, uw, sgw, suw,
                                                gwb, uwb, sgwb, suwb);
    build_lists<<<NEXP, 256, 0, stream>>>(pickE, cnt, tokList, slotList);
    plan_kernel<<<1, 64, 0, stream>>>(cnt, meta);

    gu_gemm<<<GU_GRID + 512, 256, 0, stream>>>(xb, gwb, uwb, sgwb, suwb,
                                               hiddenP, hiddenS, tokList, meta,
                                               dw, sdw, dwb, sdwb);
    dn_gemm<<<DN_GRID, 256, 0, stream>>>(hiddenP, hiddenS, dwb, sdwb,
                                         outPairs, sharedOut, slotList, meta);

    combine_kernel<<<(T_TOK * H / 8) / 256, 256, 0, stream>>>(outPairs, sharedOut, pairW, out);
}